// Round 9
// baseline (224.753 us; speedup 1.0000x reference)
//
#include <hip/hip_runtime.h>

// HistogramLoss on MI355X — fused pairwise-cosine + soft-histogram + loss.
// Round 9: de-atomize the global histogram reduction. R4-R8 invariant
// ~155-176 µs wall with all pipes idle was the 528-blocks x 302-address
// global fp32 atomic storm (WRITE_SIZE 643.5 KB == atomic bytes, write-
// through + ~40cyc/serialized-atomic = ~150 µs tail). Blocks now write
// private partial columns with plain stores; a 303-wave reduce kernel sums
// them. GEMM/epilogue identical to the absmax-0.0 Round-8 kernel.

#define N_PTS   4096
#define DIM     512
#define TSIZE   151
#define HALF_T  75
#define BM      128
#define BK      64                  // u16 elems per row per tile (128B rows)
#define NSTEP   24                  // K' = 3*512 / BK
#define NPAIR   528                 // 32*33/2 tile pairs
#define P_TOTAL 8386560u
#define STEPF   (2.0f / 150.0f)
#define STEPINV 75.0f
#define NCOPY   8
#define HSTRIDE 309                 // mod 32 = 21: copies bank-distinct
#define GRID    576                 // 8 XCD lists x 72 slots (48 idle)
#define NROWS   (2 * TSIZE + 1)     // 302 bins + 1 posCount row

typedef short bfrag __attribute__((ext_vector_type(8)));   // 8 bf16
typedef float ffrag __attribute__((ext_vector_type(4)));   // 4 f32
typedef unsigned short u16;
typedef unsigned int   u32;

__device__ __forceinline__ ffrag mfma16(bfrag a, bfrag b, ffrag c) {
  return __builtin_amdgcn_mfma_f32_16x16x32_bf16(a, b, c, 0, 0, 0);
}

__device__ __forceinline__ void split4(float4 v, uint2* hi, uint2* lo) {
  u32 u0 = __float_as_uint(v.x), u1 = __float_as_uint(v.y);
  u32 u2 = __float_as_uint(v.z), u3 = __float_as_uint(v.w);
  float r0 = v.x - __uint_as_float(u0 & 0xFFFF0000u);   // exact residual
  float r1 = v.y - __uint_as_float(u1 & 0xFFFF0000u);
  float r2 = v.z - __uint_as_float(u2 & 0xFFFF0000u);
  float r3 = v.w - __uint_as_float(u3 & 0xFFFF0000u);
  hi->x = (u0 >> 16) | (u1 & 0xFFFF0000u);
  hi->y = (u2 >> 16) | (u3 & 0xFFFF0000u);
  lo->x = (__float_as_uint(r0) >> 16) | (__float_as_uint(r1) & 0xFFFF0000u);
  lo->y = (__float_as_uint(r2) >> 16) | (__float_as_uint(r3) & 0xFFFF0000u);
}

// XCD-clique pair decode (as Round 8): each XCD touches a <=4MB panel set.
__device__ __forceinline__ bool tile_decode(int bid, int* bi_, int* bj_) {
  const int xcd = bid & 7, slot = bid >> 3;
  if (xcd < 6) {
    if (slot >= 64) return false;
    const int BA[6] = {0, 0, 0, 1, 1, 2};
    const int BB[6] = {1, 2, 3, 2, 3, 3};
    *bi_ = BA[xcd] * 8 + (slot >> 3);
    *bj_ = BB[xcd] * 8 + (slot & 7);
  } else {
    int p = slot;
    int band = (xcd - 6) * 2 + (p >= 36 ? 1 : 0);
    if (p >= 36) p -= 36;
    int rem = p, cnt = 8, ii = 0;
    while (rem >= cnt) { rem -= cnt; --cnt; ++ii; }
    *bi_ = band * 8 + ii;
    *bj_ = band * 8 + ii + rem;
  }
  return true;
}

// canonical upper-tri pair index 0..527
__device__ __forceinline__ int pair_index(int bi, int bj) {
  return bi * 32 - bi * (bi - 1) / 2 + (bj - bi);
}

// stage one 128x64 A-tile + B-tile for virtual-K step s (pre-swizzled source,
// linear global_load_lds dest — rule #21).
__device__ __forceinline__ void stage_step(
    int s, u16* Ad, u16* Bd,
    const u16* __restrict__ Fhi, const u16* __restrict__ Flo,
    int rowA, int rowB, int w, int rseg, int swzk)
{
  const int region = s >> 3;                 // 0: hi*hi, 1: lo*hi, 2: hi*lo
  const int k0 = (s & 7) * BK;
  const u16* ap = (region == 1) ? Flo : Fhi;
  const u16* bp = (region == 2) ? Flo : Fhi;
  #pragma unroll
  for (int g = 0; g < 4; ++g) {
    int seg = w * 4 + g;                     // 1KB segment = 8 rows
    int row = seg * 8 + rseg;
    size_t ga = (size_t)(rowA + row) * DIM + k0 + swzk;
    size_t gb = (size_t)(rowB + row) * DIM + k0 + swzk;
    __builtin_amdgcn_global_load_lds(
        (const __attribute__((address_space(1))) unsigned int*)(ap + ga),
        (__attribute__((address_space(3))) unsigned int*)(Ad + seg * 512),
        16, 0, 0);
    __builtin_amdgcn_global_load_lds(
        (const __attribute__((address_space(1))) unsigned int*)(bp + gb),
        (__attribute__((address_space(3))) unsigned int*)(Bd + seg * 512),
        16, 0, 0);
  }
}

__device__ __forceinline__ void compute_step(
    const u16* As, const u16* Bs, ffrag (&acc)[4][4],
    int wy, int wx, int l4, int l16)
{
  const int swz = (l16 & 7) << 3;
  #pragma unroll
  for (int ks = 0; ks < 2; ++ks) {
    bfrag a[4], b[4];
    #pragma unroll
    for (int f = 0; f < 4; ++f) {
      int ra = wy * 64 + f * 16 + l16;
      int rb = wx * 64 + f * 16 + l16;
      int ko = (ks * 32 + l4 * 8) ^ swz;
      a[f] = *(const bfrag*)(As + ra * BK + ko);
      b[f] = *(const bfrag*)(Bs + rb * BK + ko);
    }
    #pragma unroll
    for (int fj = 0; fj < 4; ++fj)
      #pragma unroll
      for (int fi = 0; fi < 4; ++fi)
        acc[fi][fj] = mfma16(a[fi], b[fj], acc[fi][fj]);
  }
}

__device__ __forceinline__ void bin_epilogue(
    const ffrag (&acc)[4][4], float* h, const int* clsA, const int* clsB,
    int wy, int wx, int l4, int l16, bool diag, u32* myPos)
{
  #pragma unroll
  for (int fi = 0; fi < 4; ++fi) {
    #pragma unroll
    for (int fj = 0; fj < 4; ++fj) {
      #pragma unroll
      for (int r = 0; r < 4; ++r) {
        // C/D layout (m89/m91): row = 4*(lane>>4)+reg, col = lane&15
        int li = wy * 64 + fi * 16 + l4 * 4 + r;
        int lj = wx * 64 + fj * 16 + l16;
        if (diag && li >= lj) continue;
        float s  = acc[fi][fj][r];
        float jf = floorf(s * STEPINV);
        int   jb = (int)jf + HALF_T;
        float f  = jf * STEPF;
        float wa = (s - f) * STEPINV;
        float wb = (f + STEPF - s) * STEPINV;
        bool  pos = (clsA[li] == clsB[lj]);
        *myPos += pos ? 1u : 0u;
        int off = pos ? 0 : TSIZE;
        if (jb >= 0 && jb < TSIZE)         unsafeAtomicAdd(h + off + jb, wa);
        if (jb + 1 >= 0 && jb + 1 < TSIZE) unsafeAtomicAdd(h + off + jb + 1, wb);
      }
    }
  }
}

// ---- pass 1: split F -> row-major bf16 planes Fhi/Flo [4096][512] ----
__global__ __launch_bounds__(256) void presplit(
    const float* __restrict__ F, u16* __restrict__ Fhi, u16* __restrict__ Flo,
    float* __restrict__ g_hist)
{
  int u = blockIdx.x * 256 + threadIdx.x;   // u = row*64 + kb
  int row = u >> 6, kb = u & 63;
  const float* src = F + (size_t)row * DIM + kb * 8;
  float4 v0 = *(const float4*)(src);
  float4 v1 = *(const float4*)(src + 4);
  uint2 h0, l0, h1, l1;
  split4(v0, &h0, &l0);
  split4(v1, &h1, &l1);
  uint4 hv; hv.x = h0.x; hv.y = h0.y; hv.z = h1.x; hv.w = h1.y;
  uint4 lv; lv.x = l0.x; lv.y = l0.y; lv.z = l1.x; lv.w = l1.y;
  size_t dst = (size_t)row * DIM + kb * 8;  // coalesced reads AND writes
  *(uint4*)(Fhi + dst) = hv;
  *(uint4*)(Flo + dst) = lv;
  if (blockIdx.x == 0) {                    // needed only by atomic fallback
    for (int i = threadIdx.x; i < NROWS; i += 256) g_hist[i] = 0.0f;
  }
}

// ---- pass 2: MFMA GEMM + binning; PART=1 -> plain-store partials ----
template <int PART>
__global__ __launch_bounds__(256, 3) void hist_mfma(
    const u16* __restrict__ Fhi, const u16* __restrict__ Flo,
    const int* __restrict__ cls,
    float* __restrict__ g_hist, float* __restrict__ partial)
{
  __shared__ __align__(16) u16 As[BM * BK];    // 16 KB
  __shared__ __align__(16) u16 Bs[BM * BK];    // 16 KB
  __shared__ float hist[NCOPY * HSTRIDE];      // 9.9 KB
  __shared__ int clsA[BM], clsB[BM];
  __shared__ u32 posCount;

  int bi, bj;
  if (!tile_decode((int)blockIdx.x, &bi, &bj)) return;   // idle slot
  const int t = threadIdx.x;
  const int rowA = bi * BM, rowB = bj * BM;

  for (int i = t; i < NCOPY * HSTRIDE; i += 256) hist[i] = 0.0f;
  if (t < BM) clsA[t] = cls[rowA + t];
  else        clsB[t - BM] = cls[rowB + (t - BM)];
  if (t == 0) posCount = 0u;

  const int lane = t & 63, w = t >> 6;
  const int wy = w >> 1, wx = w & 1;          // wave -> 64x64 quadrant
  const int l4 = lane >> 4, l16 = lane & 15;
  const int rseg = lane >> 3;                 // row within 8-row segment
  const int swzk = ((lane & 7) ^ (lane >> 3)) << 3;   // pre-swizzle, u16 units

  ffrag acc[4][4] = {};

  #pragma unroll 1
  for (int s = 0; s < NSTEP; ++s) {
    __syncthreads();                          // prev compute done (+init vis)
    stage_step(s, As, Bs, Fhi, Flo, rowA, rowB, w, rseg, swzk);
    __syncthreads();                          // vmcnt(0) drain
    compute_step(As, Bs, acc, wy, wx, l4, l16);
  }

  u32 myPos = 0;
  float* h = hist + (lane & 7) * HSTRIDE;     // adjacent lanes -> distinct copies
  bin_epilogue(acc, h, clsA, clsB, wy, wx, l4, l16, bi == bj, &myPos);
  atomicAdd(&posCount, myPos);
  __syncthreads();

  if (PART) {
    // plain stores to this pair's private column — no global atomics
    const int p = pair_index(bi, bj);
    for (int i = t; i < 2 * TSIZE; i += 256) {
      float v = 0.0f;
      #pragma unroll
      for (int c = 0; c < NCOPY; ++c) v += hist[c * HSTRIDE + i];
      partial[(size_t)i * NPAIR + p] = v;
    }
    if (t == 0) partial[(size_t)(2 * TSIZE) * NPAIR + p] = (float)posCount;
  } else {
    for (int i = t; i < 2 * TSIZE; i += 256) {
      float v = 0.0f;
      #pragma unroll
      for (int c = 0; c < NCOPY; ++c) v += hist[c * HSTRIDE + i];
      unsafeAtomicAdd(g_hist + i, v);
    }
    if (t == 0) unsafeAtomicAdd(g_hist + 2 * TSIZE, (float)posCount);
  }
}

// ---- pass 3: sum partial columns -> g_hist (one wave per row) ----
__global__ __launch_bounds__(256) void reduce_partials(
    const float* __restrict__ partial, float* __restrict__ g_hist)
{
  const int wv = blockIdx.x * 4 + (threadIdx.x >> 6);
  const int lane = threadIdx.x & 63;
  if (wv >= NROWS) return;
  float s = 0.0f;
  for (int p = lane; p < NPAIR; p += 64) s += partial[(size_t)wv * NPAIR + p];
  #pragma unroll
  for (int o = 32; o > 0; o >>= 1) s += __shfl_down(s, o);
  if (lane == 0) g_hist[wv] = s;
}

// ---- pass 4: cumsum + dot -> loss ----
__global__ __launch_bounds__(256) void finalize(
    const float* __restrict__ g_hist, float* __restrict__ out)
{
  __shared__ float hp[TSIZE];
  __shared__ float hn[TSIZE];
  __shared__ float red[4];
  const int t = threadIdx.x;
  const float Np = g_hist[2 * TSIZE];               // exact (integer < 2^24)
  const float Nn = (float)P_TOTAL - Np;
  if (t < TSIZE) {
    hp[t] = g_hist[t] / Np;
    hn[t] = g_hist[TSIZE + t] / Nn;
  }
  __syncthreads();
  for (int off = 1; off < TSIZE; off <<= 1) {
    float v = 0.0f;
    if (t < TSIZE && t >= off) v = hp[t - off];
    __syncthreads();
    if (t < TSIZE) hp[t] += v;
    __syncthreads();
  }
  float term = (t < TSIZE) ? hn[t] * hp[t] : 0.0f;
  #pragma unroll
  for (int o = 32; o > 0; o >>= 1) term += __shfl_down(term, o);
  if ((t & 63) == 0) red[t >> 6] = term;
  __syncthreads();
  if (t == 0) *out = red[0] + red[1] + red[2] + red[3];
}

extern "C" void kernel_launch(void* const* d_in, const int* in_sizes, int n_in,
                              void* d_out, int out_size, void* d_ws, size_t ws_size,
                              hipStream_t stream) {
  const float* F   = (const float*)d_in[0];
  const int*   cls = (const int*)d_in[1];
  float* g_hist = (float*)d_ws;               // NROWS floats
  float* out = (float*)d_out;

  const size_t offH   = 65536;
  const size_t bytesP = (size_t)N_PTS * DIM * sizeof(u16);       // 4 MB
  const size_t offPar = offH + 2 * bytesP;                       // 8.45 MB
  const size_t bytesPar = (size_t)NROWS * NPAIR * sizeof(float); // 640 KB
  u16* Fhi = (u16*)((char*)d_ws + offH);
  u16* Flo = (u16*)((char*)d_ws + offH + bytesP);

  presplit<<<(N_PTS * 64) / 256, 256, 0, stream>>>(F, Fhi, Flo, g_hist);
  if (ws_size >= offPar + bytesPar) {
    float* partial = (float*)((char*)d_ws + offPar);
    hist_mfma<1><<<GRID, 256, 0, stream>>>(Fhi, Flo, cls, g_hist, partial);
    reduce_partials<<<(NROWS + 3) / 4, 256, 0, stream>>>(partial, g_hist);
  } else {
    hist_mfma<0><<<GRID, 256, 0, stream>>>(Fhi, Flo, cls, g_hist, nullptr);
  }
  finalize<<<1, 256, 0, stream>>>(g_hist, out);
}